// Round 1
// baseline (38.101 us; speedup 1.0000x reference)
//
#include <hip/hip_runtime.h>
#include <math.h>

#define H 150
#define G 600          // 4*H
#define STEPS 10
#define GRIDA 128      // kernel A blocks: 24 for gx, rest transpose W_hh

__device__ __forceinline__ float sigm(float x) {
    return 1.0f / (1.0f + expf(-x));
}

// ---------------- Kernel A: parallel gx + W_hh transpose/prefetch ----------------
__global__ __launch_bounds__(256) void lstm_prep_kernel(
    const float* __restrict__ inputx, const float* __restrict__ W_ih,
    const float* __restrict__ W_hh, const float* __restrict__ b_ih,
    const float* __restrict__ b_hh, const int* __restrict__ xp,
    float* __restrict__ gx, float* __restrict__ Wt)
{
    const int b = blockIdx.x;
    if (b < 24) {
        // gx[t*G+g] = W_ih[g,:] . xs[t,:] + b_ih[g] + b_hh[g]
        int gid = b * 256 + threadIdx.x;
        if (gid < STEPS * G) {
            int t = gid / G;
            int g = gid - t * G;
            const float* xrow = inputx + (xp[0] - STEPS + t) * H;
            const float* wrow = W_ih + g * H;
            float acc = 0.f;
            #pragma unroll
            for (int k = 0; k < H; k += 2) {
                float2 wv = *reinterpret_cast<const float2*>(wrow + k);
                float2 xv = *reinterpret_cast<const float2*>(xrow + k);
                acc += wv.x * xv.x + wv.y * xv.y;
            }
            gx[gid] = acc + b_ih[g] + b_hh[g];
        }
    } else {
        // transpose W_hh (coalesced read) -> Wt[k*G+g]; also warms L2/L3
        for (int i = (b - 24) * 256 + threadIdx.x; i < G * H;
             i += (GRIDA - 24) * 256) {
            int g = i / H;
            int k = i - g * H;
            Wt[k * G + g] = W_hh[i];
        }
    }
}

// ---------------- Kernel B: single-block recurrent loop ----------------
// FUSED=false: Wsrc = transposed W_hh in ws (coalesced reg load), gxsrc = ws
// FUSED=true : everything computed in-kernel (ws-free fallback)
template<bool FUSED>
__global__ __launch_bounds__(640, 3) void lstm_rec_kernel(
    const float* __restrict__ inputx, const float* __restrict__ W_ih,
    const float* __restrict__ Wsrc, const float* __restrict__ b_ih,
    const float* __restrict__ b_hh, const int* __restrict__ xp,
    const float* __restrict__ gxsrc, float* __restrict__ out)
{
    __shared__ float s_h[H];
    __shared__ float s_c[H];
    __shared__ float s_gate[G];
    __shared__ float s_x[FUSED ? STEPS * H : 1];
    __shared__ float s_gx[FUSED ? STEPS * G : 1];

    const int tid = threadIdx.x;

    if (tid < H) { s_h[tid] = 0.f; s_c[tid] = 0.f; }

    if constexpr (FUSED) {
        const int x0 = (xp[0] - STEPS) * H;
        for (int i = tid; i < STEPS * H; i += 640) s_x[i] = inputx[x0 + i];
        __syncthreads();
        if (tid < G) {
            float acc[STEPS];
            #pragma unroll
            for (int t = 0; t < STEPS; ++t) acc[t] = 0.f;
            const float* wrow = W_ih + tid * H;
            for (int k = 0; k < H; k += 2) {
                float2 wv = *reinterpret_cast<const float2*>(wrow + k);
                #pragma unroll
                for (int t = 0; t < STEPS; ++t)
                    acc[t] += wv.x * s_x[t * H + k] + wv.y * s_x[t * H + k + 1];
            }
            float bias = b_ih[tid] + b_hh[tid];
            #pragma unroll
            for (int t = 0; t < STEPS; ++t) s_gx[t * G + tid] = acc[t] + bias;
        }
    }

    // W_hh row for this gate -> registers
    float w[H];
    if (tid < G) {
        if constexpr (FUSED) {
            const float* r = Wsrc + tid * H;   // row-major W_hh (strided load)
            #pragma unroll
            for (int k = 0; k < H; k += 2) {
                float2 v = *reinterpret_cast<const float2*>(r + k);
                w[k] = v.x; w[k + 1] = v.y;
            }
        } else {
            #pragma unroll
            for (int k = 0; k < H; ++k) w[k] = Wsrc[k * G + tid];  // coalesced
        }
    }
    __syncthreads();

    for (int t = 0; t < STEPS; ++t) {
        if (tid < G) {
            float gxi;
            if constexpr (FUSED) gxi = s_gx[t * G + tid];
            else                 gxi = gxsrc[t * G + tid];   // issued early, hidden under dot
            float acc0 = 0.f, acc1 = 0.f;
            #pragma unroll
            for (int k = 0; k < H; k += 2) {
                acc0 += w[k]     * s_h[k];
                acc1 += w[k + 1] * s_h[k + 1];
            }
            s_gate[tid] = acc0 + acc1 + gxi;
        }
        __syncthreads();
        if (tid < H) {
            float ig = s_gate[tid];
            float fg = s_gate[H + tid];
            float gg = s_gate[2 * H + tid];
            float og = s_gate[3 * H + tid];
            float c  = s_c[tid];
            float cn = sigm(fg) * c + sigm(ig) * tanhf(gg);
            float hn = sigm(og) * tanhf(cn);
            s_c[tid] = cn;
            s_h[tid] = hn;
        }
        __syncthreads();
    }

    if (tid < H) out[tid] = s_h[tid];
}

extern "C" void kernel_launch(void* const* d_in, const int* in_sizes, int n_in,
                              void* d_out, int out_size, void* d_ws, size_t ws_size,
                              hipStream_t stream) {
    const float* inputx = (const float*)d_in[0];
    const float* W_ih   = (const float*)d_in[1];
    const float* W_hh   = (const float*)d_in[2];
    const float* b_ih   = (const float*)d_in[3];
    const float* b_hh   = (const float*)d_in[4];
    const int*   xp     = (const int*)d_in[5];
    float* out = (float*)d_out;

    const size_t need = (size_t)(STEPS * G + G * H) * sizeof(float); // gx + Wt
    if (ws_size >= need) {
        float* gx = (float*)d_ws;            // 6000 floats
        float* Wt = gx + STEPS * G;          // 90000 floats
        lstm_prep_kernel<<<GRIDA, 256, 0, stream>>>(inputx, W_ih, W_hh, b_ih,
                                                    b_hh, xp, gx, Wt);
        lstm_rec_kernel<false><<<1, 640, 0, stream>>>(inputx, W_ih, Wt, b_ih,
                                                      b_hh, xp, gx, out);
    } else {
        lstm_rec_kernel<true><<<1, 640, 0, stream>>>(inputx, W_ih, W_hh, b_ih,
                                                     b_hh, xp, nullptr, out);
    }
}